// Round 26
// baseline (123.096 us; speedup 1.0000x reference)
//
#include <hip/hip_runtime.h>
#include <hip/hip_bf16.h>
#include <stdint.h>

#define B_ 2
#define N_ 2048
#define H_ 16
#define DIM_ 1024
#define NH3 3072
#define ROWS (B_*N_)   // 4096
#define BHN (B_*H_*N_) // 65536

typedef __attribute__((ext_vector_type(8))) short bf16x8;
typedef __attribute__((ext_vector_type(4))) float f32x4;
typedef unsigned short u16;

__device__ __forceinline__ u16 f2bf(float f){
  union { float f; uint32_t u; } v; v.f = f;
  return (u16)((v.u + 0x7fffu + ((v.u >> 16) & 1u)) >> 16);
}

#if __has_builtin(__builtin_amdgcn_exp2f)
#define EXP2F(x) __builtin_amdgcn_exp2f(x)
#else
#define EXP2F(x) __expf((x) * 0.6931471805599453f)
#endif
#if __has_builtin(__builtin_amdgcn_rcpf)
#define RCPF(x) __builtin_amdgcn_rcpf(x)
#else
#define RCPF(x) (1.0f / (x))
#endif

#define GLL16(g, l) __builtin_amdgcn_global_load_lds( \
    (const __attribute__((address_space(1))) void*)(g), \
    (__attribute__((address_space(3))) void*)(l), 16, 0, 0)

// ---------------- fused prep: rmsnorm (0..4095) | transpose (4096..8191) | rope (8192..8703) ----------------
__global__ __launch_bounds__(256) void k_prep(
    const float* __restrict__ x, const float* __restrict__ gamma,
    const float* __restrict__ wqkv, const float* __restrict__ wout,
    const int* __restrict__ mods,
    u16* __restrict__ xn, u16* __restrict__ wqkvT, u16* __restrict__ woutT,
    float* __restrict__ cosT, float* __restrict__ sinT)
{
  __shared__ float tile[32][33];
  const int bx = blockIdx.x;
  const int tid = threadIdx.x;
  if (bx < 4096){
    const int row = bx;
    const float4 xv = ((const float4*)(x + (size_t)row*DIM_))[tid];
    float ss = xv.x*xv.x + xv.y*xv.y + xv.z*xv.z + xv.w*xv.w;
#pragma unroll
    for (int d = 1; d < 64; d <<= 1) ss += __shfl_xor(ss, d);
    if ((tid & 63) == 0) tile[1][tid >> 6] = ss;
    __syncthreads();
    float tot = tile[1][0] + tile[1][1] + tile[1][2] + tile[1][3];
    float scl = 32.0f / fmaxf(sqrtf(tot), 1e-12f);   // sqrt(1024)=32
    const float4 gv = ((const float4*)gamma)[tid];
    ushort4 o;
    o.x = f2bf(xv.x * scl * (gv.x + 1.0f));
    o.y = f2bf(xv.y * scl * (gv.y + 1.0f));
    o.z = f2bf(xv.z * scl * (gv.z + 1.0f));
    o.w = f2bf(xv.w * scl * (gv.w + 1.0f));
    ((ushort4*)(xn + (size_t)row*DIM_))[tid] = o;
  } else if (bx < 8192){
    const int t = bx - 4096;
    const int bxx = t & 127, by = t >> 7;
    const float* src; u16* dst; int C, bc;
    if (bxx < 96){ src = wqkv; dst = wqkvT; C = NH3;  bc = bxx*32; }
    else         { src = wout; dst = woutT; C = DIM_; bc = (bxx-96)*32; }
    const int R = DIM_;
    const int tx = tid & 31, ty = tid >> 5;
    const int br = by * 32;
#pragma unroll
    for (int i = 0; i < 32; i += 8)
      tile[ty + i][tx] = src[(size_t)(br + ty + i)*C + bc + tx];
    __syncthreads();
#pragma unroll
    for (int i = 0; i < 32; i += 8)
      dst[(size_t)(bc + ty + i)*R + br + tx] = f2bf(tile[tx][ty + i]);
  } else {
    const int t = (bx - 8192)*256 + tid;
    const int f = t & 31, bn = t >> 5;
    const int b = bn >> 11, n = bn & (N_-1);
    int cum = 0;
#pragma unroll
    for (int m = 0; m < 4; ++m){
      const int off = mods[(b*4 + m)*3 + 1];
      const int len = mods[(b*4 + m)*3 + 2];
      cum += min(max(n - off, 0), len - 1);
    }
    const float pos = (float)(n - cum);
    // 10000^(-f/32) = exp2(-f * log2(10000)/32)
    const float inv = EXP2F((float)f * -0.41524101186092029f);
    float s, c;
    sincosf(pos * inv, &s, &c);
    cosT[t] = c; sinT[t] = s;
  }
}

// ---------------- BMx128 bf16 MFMA GEMM: C = A @ Bt^T ----------------
// DEPTH: K-steps staged per barrier pair into separate buffers (fewer drains)
template<int MODE, int BM, int DEPTH>
__global__ __launch_bounds__(256) void k_gemm(
    const u16* __restrict__ A, const u16* __restrict__ Bt,
    int K, int Nc,
    float* __restrict__ outf,
    const float* __restrict__ cosT, const float* __restrict__ sinT,
    u16* __restrict__ qo, u16* __restrict__ ko, u16* __restrict__ vt)
{
  constexpr int MR = BM/32;
  constexpr int RA = BM/8;
  constexpr int CNT = (RA + 16)/4;
  __shared__ u16 lA[DEPTH][BM*64];
  __shared__ u16 lB[DEPTH][128*64];
  const int tid = threadIdx.x;
  const int wid = tid >> 6, lane = tid & 63;
  const int nx = gridDim.x;
  const int orig = blockIdx.y * nx + blockIdx.x;
  const int qq = (nx * gridDim.y) >> 3;
  const int wgid = (orig & 7) * qq + (orig >> 3);
  const int m0 = (wgid % nx) * BM, n0 = (wgid / nx) * 128;
  const int wm = wid >> 1, wn = wid & 1;
  const int srow = lane >> 3, sch = lane & 7;
  const int r16 = lane & 15, g4 = lane >> 4;
  f32x4 acc[MR][4] = {};
  const int ksteps = K >> 6;

  auto stage2 = [&](int kt, int bi){
    const int kb = kt*64;
    const int gch = sch ^ srow;
#pragma unroll
    for (int i = 0; i < CNT; ++i){
      const int reg = wid*CNT + i;
      if (reg < RA){
        const int row = reg*8 + srow;
        GLL16(A + (size_t)(m0 + row)*K + kb + gch*8, &lA[bi][reg*512]);
      } else {
        const int r2 = reg - RA;
        const int row = r2*8 + srow;
        GLL16(Bt + (size_t)(n0 + row)*K + kb + gch*8, &lB[bi][r2*512]);
      }
    }
  };
  auto compute = [&](int bi){
#pragma unroll
    for (int t = 0; t < 2; ++t){
      bf16x8 af[MR], bfr[4];
#pragma unroll
      for (int m = 0; m < MR; ++m){
        int row = wm*(BM/2) + m*16 + r16;
        int ch = (t*4 + g4) ^ (r16 & 7);
        af[m] = *(const bf16x8*)&lA[bi][row*64 + ch*8];
      }
#pragma unroll
      for (int n = 0; n < 4; ++n){
        int row = wn*64 + n*16 + r16;
        int ch = (t*4 + g4) ^ (r16 & 7);
        bfr[n] = *(const bf16x8*)&lB[bi][row*64 + ch*8];
      }
#pragma unroll
      for (int m = 0; m < MR; ++m)
#pragma unroll
        for (int n = 0; n < 4; ++n)
          acc[m][n] = __builtin_amdgcn_mfma_f32_16x16x32_bf16(af[m], bfr[n], acc[m][n], 0, 0, 0);
    }
  };

  for (int kt = 0; kt < ksteps; kt += DEPTH){
    __syncthreads();                 // previous-group readers done
#pragma unroll
    for (int d = 0; d < DEPTH; ++d)
      if (kt + d < ksteps) stage2(kt + d, d);
    __syncthreads();                 // all staged (one vmcnt drain)
#pragma unroll
    for (int d = 0; d < DEPTH; ++d)
      if (kt + d < ksteps) compute(d);
  }
#pragma unroll
  for (int m = 0; m < MR; ++m){
#pragma unroll
    for (int n = 0; n < 4; ++n){
      if constexpr (MODE == 0){
        const int gcol = n0 + wn*64 + n*16 + r16;
        const int s3 = gcol >> 10, hh = (gcol >> 6) & 15, d = gcol & 63;
        const int grow0 = m0 + wm*(BM/2) + m*16 + g4*4;
        const int b = grow0 >> 11, nn0 = grow0 & (N_-1);
        const size_t hb = (size_t)(b*H_ + hh);
        if (s3 == 2){
          uint32_t w01, w23;
          asm("v_cvt_pk_bf16_f32 %0, %1, %2" : "=v"(w01) : "v"(acc[m][n][0]), "v"(acc[m][n][1]));
          asm("v_cvt_pk_bf16_f32 %0, %1, %2" : "=v"(w23) : "v"(acc[m][n][2]), "v"(acc[m][n][3]));
          *reinterpret_cast<uint2*>(&vt[(hb*64 + d)*N_ + nn0]) = make_uint2(w01, w23);
        } else {
#pragma unroll
          for (int r = 0; r < 4; ++r){
            const float v = acc[m][n][r];
            const float part = __shfl_xor(v, 1);
            const int nn = nn0 + r;
            const int pidx = (b*N_ + nn)*32 + (d >> 1);
            const float c = cosT[pidx], sn = sinT[pidx];
            const float rot = (d & 1) ? (v*c + part*sn) : (v*c - part*sn);
            const u16 val = f2bf(rot);
            if (s3 == 0) qo[(hb*N_ + nn)*64 + d] = val;
            else         ko[(hb*N_ + nn)*64 + d] = val;
          }
        }
      } else {
#pragma unroll
        for (int r = 0; r < 4; ++r){
          const int grow = m0 + wm*(BM/2) + m*16 + g4*4 + r;
          const int gcol = n0 + wn*64 + n*16 + r16;
          outf[(size_t)grow*Nc + gcol] = acc[m][n][r];
        }
      }
    }
  }
}

// ---------------- fused attention: QBLK=128 (8 waves), quad-tile staging ----------------
// Drain-reduction mechanism at depth 4: LDS 72.7KB <= 80KB/block at the
// grid-capped 2 blocks/CU, so occupancy is unchanged; barrier groups 11 -> 8.
#define PST 68   // P LDS row stride: 34 dwords -> uniform bank distribution for b64 ops
__global__ __launch_bounds__(512) void k_attn(
    const u16* __restrict__ qb, const u16* __restrict__ kb, const u16* __restrict__ vt,
    const int* __restrict__ mods, u16* __restrict__ xo)
{
  __shared__ u16 lK[4][64*64];
  __shared__ u16 lV[4][64*64];
  __shared__ u16 lP[8*16*PST];
  const int tid = threadIdx.x, wid = tid >> 6, lane = tid & 63;
  const int id = blockIdx.x;          // 0..511
  const int xcd = id & 7, rank = id >> 3;   // rank 0..63 per XCD
  const int bh = xcd + 8*(rank & 3);
  const int qslot = rank >> 2;        // 0..15
  const int tp = (qslot < 8) ? (15 - qslot) : (qslot - 8);  // complementary pairs
  const int b = bh >> 4, h = bh & 15;
  const int r16 = lane & 15, g4 = lane >> 4;
  const int srow = lane >> 3, sch = lane & 7;
  int moff[4], mend[4];
#pragma unroll
  for (int m = 0; m < 4; ++m){
    moff[m] = mods[(b*4+m)*3+1];
    mend[m] = moff[m] + mods[(b*4+m)*3+2];
  }
  const u16* kbase = kb + (size_t)bh*N_*64;
  const u16* vbase = vt + (size_t)bh*64*N_;
  u16* lPw = &lP[wid*16*PST];

  const int q0 = tp*128 + wid*16;     // this wave's 16 q-rows
  const int i  = q0 + r16;            // this lane's q-row
  const int imax = tp*128 + 127;      // block max q-row (block-uniform skip)
  int jmax = 0, jmax0 = 0;
#pragma unroll
  for (int m = 0; m < 4; ++m){
    if (i  >= moff[m]) jmax  = max(jmax,  mend[m]);
    if (q0 >= moff[m]) jmax0 = max(jmax0, mend[m]);
  }
  const int thrmin = max(q0, jmax0 - 1);   // wave-uniform lower bound of thr
  const int thrg = max(i, jmax - 1);       // per-lane keep threshold (global)
  const u16* qrow = qb + ((size_t)bh*N_ + q0 + r16)*64;
  const bf16x8 aq0 = *(const bf16x8*)&qrow[g4*8];
  const bf16x8 aq1 = *(const bf16x8*)&qrow[32 + g4*8];
  f32x4 o[4] = {};
  f32x4 acc_s = {};                      // row-sum accumulator (ones-MFMA)
  bf16x8 ones;
#pragma unroll
  for (int j = 0; j < 8; ++j) ones[j] = (short)0x3F80;  // bf16 1.0

  // g2(s) = 50*tanh(s*0.125/50)*log2e as odd series in s (w = s^2), 2 terms
  const float D1 = 0.18033688011112043f;
  const float D3 = -3.7570183356483704e-07f;

  auto proc = [&](int kt)->bool{
    if (kt >= 32) return false;
    if (kt*64 <= imax) return true;
    bool p = false;
#pragma unroll
    for (int m = 0; m < 4; ++m)
      if (imax >= moff[m] && kt*64 < mend[m]) p = true;
    return p;
  };

  auto computeHalf = [&](int kt, const u16* lKc, const u16* lVc){
    // S^T = K @ Q^T : lane holds q = q0+r16, k_local = cb*16 + g4*4 + r
    f32x4 s[4] = {};
    __builtin_amdgcn_s_setprio(1);
#pragma unroll
    for (int cb = 0; cb < 4; ++cb){
#pragma unroll
      for (int t = 0; t < 2; ++t){
        int row = cb*16 + r16;
        int ch = (t*4 + g4) ^ (row & 7);
        bf16x8 bk = *(const bf16x8*)&lKc[row*64 + ch*8];
        s[cb] = __builtin_amdgcn_mfma_f32_16x16x32_bf16(bk, t ? aq1 : aq0, s[cb], 0, 0, 0);
      }
    }
    __builtin_amdgcn_s_setprio(0);
    const int thr = thrg - kt*64;                    // keep <=> k_local <= thr
    const bool nomask = (kt*64 + 63 <= thrmin);      // wave-uniform fully-kept tile
#pragma unroll
    for (int cb = 0; cb < 4; ++cb){
      float p[4];
#pragma unroll
      for (int r = 0; r < 4; ++r){
        const float sv = s[cb][r];
        const float w = sv*sv;
        p[r] = EXP2F(sv * fmaf(w, D3, D1));
      }
      if (!nomask){
#pragma unroll
        for (int r = 0; r < 4; ++r)
          p[r] = (cb*16 + g4*4 + r <= thr) ? p[r] : 0.0f;
      }
      uint32_t w01, w23;
      asm("v_cvt_pk_bf16_f32 %0, %1, %2" : "=v"(w01) : "v"(p[0]), "v"(p[1]));
      asm("v_cvt_pk_bf16_f32 %0, %1, %2" : "=v"(w23) : "v"(p[2]), "v"(p[3]));
      *reinterpret_cast<uint2*>(&lPw[r16*PST + cb*16 + g4*4]) = make_uint2(w01, w23);
    }
    asm volatile("s_waitcnt lgkmcnt(0)" ::: "memory");
    __builtin_amdgcn_sched_barrier(0);
    union { uint2 hh[2]; bf16x8 v; } u0, u1;
    u0.hh[0] = *(const uint2*)&lPw[r16*PST + g4*8];
    u0.hh[1] = *(const uint2*)&lPw[r16*PST + g4*8 + 4];
    u1.hh[0] = *(const uint2*)&lPw[r16*PST + 32 + g4*8];
    u1.hh[1] = *(const uint2*)&lPw[r16*PST + 32 + g4*8 + 4];
    __builtin_amdgcn_s_setprio(1);
    acc_s = __builtin_amdgcn_mfma_f32_16x16x32_bf16(u0.v, ones, acc_s, 0, 0, 0);
    acc_s = __builtin_amdgcn_mfma_f32_16x16x32_bf16(u1.v, ones, acc_s, 0, 0, 0);
#pragma unroll
    for (int cb = 0; cb < 4; ++cb){
#pragma unroll
      for (int t = 0; t < 2; ++t){
        int d = cb*16 + r16;
        int ch = (t*4 + g4) ^ (d & 7);
        bf16x8 bv = *(const bf16x8*)&lVc[d*64 + ch*8];
        o[cb] = __builtin_amdgcn_mfma_f32_16x16x32_bf16(t ? u1.v : u0.v, bv, o[cb], 0, 0, 0);
      }
    }
    __builtin_amdgcn_s_setprio(0);
  };

  auto stage = [&](int kt, int bi){
    const int gch = sch ^ srow;
    GLL16(kbase + (size_t)(kt*64 + wid*8 + srow)*64 + gch*8, &lK[bi][wid*512]);
    GLL16(vbase + (size_t)(wid*8 + srow)*N_ + kt*64 + gch*8, &lV[bi][wid*512]);
  };

  for (int base = 0; base < 32; base += 4){
    const bool pA = proc(base);
    const bool pB = proc(base + 1);
    const bool pC = proc(base + 2);
    const bool pD = proc(base + 3);
    if (!(pA || pB || pC || pD)) continue;  // block-uniform skip (whole group dead)
    __syncthreads();                    // previous-group readers done
    if (pA) stage(base,     0);
    if (pB) stage(base + 1, 1);
    if (pC) stage(base + 2, 2);
    if (pD) stage(base + 3, 3);
    __syncthreads();                    // all staged (one vmcnt drain)
    if (pA) computeHalf(base,     lK[0], lV[0]);
    if (pB) computeHalf(base + 1, lK[1], lV[1]);
    if (pC) computeHalf(base + 2, lK[2], lV[2]);
    if (pD) computeHalf(base + 3, lK[3], lV[3]);
  }
  // acc_s[r] = full row-sum for q-row g4*4+r (replicated across col lanes)
#pragma unroll
  for (int r = 0; r < 4; ++r){
    const float linv = RCPF(acc_s[r]);
    const int iq = q0 + g4*4 + r;
#pragma unroll
    for (int cb = 0; cb < 4; ++cb)
      xo[(size_t)(b*N_ + iq)*DIM_ + h*64 + cb*16 + r16] = f2bf(o[cb][r]*linv);
  }
}

extern "C" void kernel_launch(void* const* d_in, const int* in_sizes, int n_in,
                              void* d_out, int out_size, void* d_ws, size_t ws_size,
                              hipStream_t stream){
  const float* x     = (const float*)d_in[0];
  const int*   mods  = (const int*)d_in[1];
  const float* gamma = (const float*)d_in[2];
  const float* wqkv  = (const float*)d_in[3];
  const float* wout  = (const float*)d_in[4];
  float* outp = (float*)d_out;

  char* p = (char*)d_ws;
  auto alloc = [&](size_t bytes) -> char* {
    char* r = p; p += (bytes + 255) & ~(size_t)255; return r;
  };
  float* cosT  = (float*)alloc((size_t)B_*N_*32*4);
  float* sinT  = (float*)alloc((size_t)B_*N_*32*4);
  u16* wqkvT   = (u16*)alloc((size_t)NH3*DIM_*2);
  u16* woutT   = (u16*)alloc((size_t)DIM_*DIM_*2);
  u16* xn      = (u16*)alloc((size_t)ROWS*DIM_*2);
  u16* qbb     = (u16*)alloc((size_t)BHN*64*2);
  u16* kbb     = (u16*)alloc((size_t)BHN*64*2);
  u16* vtb     = (u16*)alloc((size_t)BHN*64*2);
  u16* xo      = (u16*)alloc((size_t)ROWS*DIM_*2);

  k_prep<<<8704, 256, 0, stream>>>(x, gamma, wqkv, wout, mods, xn, wqkvT, woutT, cosT, sinT);
  k_gemm<0,128,1><<<dim3(ROWS/128, NH3/128), 256, 0, stream>>>(xn, wqkvT, DIM_, NH3, nullptr, cosT, sinT, qbb, kbb, vtb);
  k_attn<<<512, 512, 0, stream>>>(qbb, kbb, vtb, mods, xo);
  k_gemm<1,64,3><<<dim3(ROWS/64, DIM_/128), 256, 0, stream>>>(xo, woutT, DIM_, DIM_, outp, nullptr, nullptr, nullptr, nullptr, nullptr);
}

// Round 27
// 108.623 us; speedup vs baseline: 1.1332x; 1.1332x over previous
//
#include <hip/hip_runtime.h>
#include <hip/hip_bf16.h>
#include <stdint.h>

#define B_ 2
#define N_ 2048
#define H_ 16
#define DIM_ 1024
#define NH3 3072
#define ROWS (B_*N_)   // 4096
#define BHN (B_*H_*N_) // 65536

typedef __attribute__((ext_vector_type(8))) short bf16x8;
typedef __attribute__((ext_vector_type(4))) float f32x4;
typedef unsigned short u16;

__device__ __forceinline__ u16 f2bf(float f){
  union { float f; uint32_t u; } v; v.f = f;
  return (u16)((v.u + 0x7fffu + ((v.u >> 16) & 1u)) >> 16);
}

#if __has_builtin(__builtin_amdgcn_exp2f)
#define EXP2F(x) __builtin_amdgcn_exp2f(x)
#else
#define EXP2F(x) __expf((x) * 0.6931471805599453f)
#endif
#if __has_builtin(__builtin_amdgcn_rcpf)
#define RCPF(x) __builtin_amdgcn_rcpf(x)
#else
#define RCPF(x) (1.0f / (x))
#endif

#define GLL16(g, l) __builtin_amdgcn_global_load_lds( \
    (const __attribute__((address_space(1))) void*)(g), \
    (__attribute__((address_space(3))) void*)(l), 16, 0, 0)

// ---------------- fused prep: rmsnorm (0..4095) | transpose (4096..8191) | rope (8192..8703) ----------------
__global__ __launch_bounds__(256) void k_prep(
    const float* __restrict__ x, const float* __restrict__ gamma,
    const float* __restrict__ wqkv, const float* __restrict__ wout,
    const int* __restrict__ mods,
    u16* __restrict__ xn, u16* __restrict__ wqkvT, u16* __restrict__ woutT,
    float* __restrict__ cosT, float* __restrict__ sinT)
{
  __shared__ float tile[32][33];
  const int bx = blockIdx.x;
  const int tid = threadIdx.x;
  if (bx < 4096){
    const int row = bx;
    const float4 xv = ((const float4*)(x + (size_t)row*DIM_))[tid];
    float ss = xv.x*xv.x + xv.y*xv.y + xv.z*xv.z + xv.w*xv.w;
#pragma unroll
    for (int d = 1; d < 64; d <<= 1) ss += __shfl_xor(ss, d);
    if ((tid & 63) == 0) tile[1][tid >> 6] = ss;
    __syncthreads();
    float tot = tile[1][0] + tile[1][1] + tile[1][2] + tile[1][3];
    float scl = 32.0f / fmaxf(sqrtf(tot), 1e-12f);   // sqrt(1024)=32
    const float4 gv = ((const float4*)gamma)[tid];
    ushort4 o;
    o.x = f2bf(xv.x * scl * (gv.x + 1.0f));
    o.y = f2bf(xv.y * scl * (gv.y + 1.0f));
    o.z = f2bf(xv.z * scl * (gv.z + 1.0f));
    o.w = f2bf(xv.w * scl * (gv.w + 1.0f));
    ((ushort4*)(xn + (size_t)row*DIM_))[tid] = o;
  } else if (bx < 8192){
    const int t = bx - 4096;
    const int bxx = t & 127, by = t >> 7;
    const float* src; u16* dst; int C, bc;
    if (bxx < 96){ src = wqkv; dst = wqkvT; C = NH3;  bc = bxx*32; }
    else         { src = wout; dst = woutT; C = DIM_; bc = (bxx-96)*32; }
    const int R = DIM_;
    const int tx = tid & 31, ty = tid >> 5;
    const int br = by * 32;
#pragma unroll
    for (int i = 0; i < 32; i += 8)
      tile[ty + i][tx] = src[(size_t)(br + ty + i)*C + bc + tx];
    __syncthreads();
#pragma unroll
    for (int i = 0; i < 32; i += 8)
      dst[(size_t)(bc + ty + i)*R + br + tx] = f2bf(tile[tx][ty + i]);
  } else {
    const int t = (bx - 8192)*256 + tid;
    const int f = t & 31, bn = t >> 5;
    const int b = bn >> 11, n = bn & (N_-1);
    int cum = 0;
#pragma unroll
    for (int m = 0; m < 4; ++m){
      const int off = mods[(b*4 + m)*3 + 1];
      const int len = mods[(b*4 + m)*3 + 2];
      cum += min(max(n - off, 0), len - 1);
    }
    const float pos = (float)(n - cum);
    // 10000^(-f/32) = exp2(-f * log2(10000)/32)
    const float inv = EXP2F((float)f * -0.41524101186092029f);
    float s, c;
    sincosf(pos * inv, &s, &c);
    cosT[t] = c; sinT[t] = s;
  }
}

// ---------------- BMx128 bf16 MFMA GEMM: C = A @ Bt^T ----------------
// DEPTH: K-steps staged per barrier pair into separate buffers (fewer drains)
template<int MODE, int BM, int DEPTH>
__global__ __launch_bounds__(256) void k_gemm(
    const u16* __restrict__ A, const u16* __restrict__ Bt,
    int K, int Nc,
    float* __restrict__ outf,
    const float* __restrict__ cosT, const float* __restrict__ sinT,
    u16* __restrict__ qo, u16* __restrict__ ko, u16* __restrict__ vt)
{
  constexpr int MR = BM/32;
  constexpr int RA = BM/8;
  constexpr int CNT = (RA + 16)/4;
  __shared__ u16 lA[DEPTH][BM*64];
  __shared__ u16 lB[DEPTH][128*64];
  const int tid = threadIdx.x;
  const int wid = tid >> 6, lane = tid & 63;
  const int nx = gridDim.x;
  const int orig = blockIdx.y * nx + blockIdx.x;
  const int qq = (nx * gridDim.y) >> 3;
  const int wgid = (orig & 7) * qq + (orig >> 3);
  const int m0 = (wgid % nx) * BM, n0 = (wgid / nx) * 128;
  const int wm = wid >> 1, wn = wid & 1;
  const int srow = lane >> 3, sch = lane & 7;
  const int r16 = lane & 15, g4 = lane >> 4;
  f32x4 acc[MR][4] = {};
  const int ksteps = K >> 6;

  auto stage2 = [&](int kt, int bi){
    const int kb = kt*64;
    const int gch = sch ^ srow;
#pragma unroll
    for (int i = 0; i < CNT; ++i){
      const int reg = wid*CNT + i;
      if (reg < RA){
        const int row = reg*8 + srow;
        GLL16(A + (size_t)(m0 + row)*K + kb + gch*8, &lA[bi][reg*512]);
      } else {
        const int r2 = reg - RA;
        const int row = r2*8 + srow;
        GLL16(Bt + (size_t)(n0 + row)*K + kb + gch*8, &lB[bi][r2*512]);
      }
    }
  };
  auto compute = [&](int bi){
#pragma unroll
    for (int t = 0; t < 2; ++t){
      bf16x8 af[MR], bfr[4];
#pragma unroll
      for (int m = 0; m < MR; ++m){
        int row = wm*(BM/2) + m*16 + r16;
        int ch = (t*4 + g4) ^ (r16 & 7);
        af[m] = *(const bf16x8*)&lA[bi][row*64 + ch*8];
      }
#pragma unroll
      for (int n = 0; n < 4; ++n){
        int row = wn*64 + n*16 + r16;
        int ch = (t*4 + g4) ^ (r16 & 7);
        bfr[n] = *(const bf16x8*)&lB[bi][row*64 + ch*8];
      }
#pragma unroll
      for (int m = 0; m < MR; ++m)
#pragma unroll
        for (int n = 0; n < 4; ++n)
          acc[m][n] = __builtin_amdgcn_mfma_f32_16x16x32_bf16(af[m], bfr[n], acc[m][n], 0, 0, 0);
    }
  };

  for (int kt = 0; kt < ksteps; kt += DEPTH){
    __syncthreads();                 // previous-group readers done
#pragma unroll
    for (int d = 0; d < DEPTH; ++d)
      if (kt + d < ksteps) stage2(kt + d, d);
    __syncthreads();                 // all staged (one vmcnt drain)
#pragma unroll
    for (int d = 0; d < DEPTH; ++d)
      if (kt + d < ksteps) compute(d);
  }
#pragma unroll
  for (int m = 0; m < MR; ++m){
#pragma unroll
    for (int n = 0; n < 4; ++n){
      if constexpr (MODE == 0){
        const int gcol = n0 + wn*64 + n*16 + r16;
        const int s3 = gcol >> 10, hh = (gcol >> 6) & 15, d = gcol & 63;
        const int grow0 = m0 + wm*(BM/2) + m*16 + g4*4;
        const int b = grow0 >> 11, nn0 = grow0 & (N_-1);
        const size_t hb = (size_t)(b*H_ + hh);
        if (s3 == 2){
          uint32_t w01, w23;
          asm("v_cvt_pk_bf16_f32 %0, %1, %2" : "=v"(w01) : "v"(acc[m][n][0]), "v"(acc[m][n][1]));
          asm("v_cvt_pk_bf16_f32 %0, %1, %2" : "=v"(w23) : "v"(acc[m][n][2]), "v"(acc[m][n][3]));
          *reinterpret_cast<uint2*>(&vt[(hb*64 + d)*N_ + nn0]) = make_uint2(w01, w23);
        } else {
#pragma unroll
          for (int r = 0; r < 4; ++r){
            const float v = acc[m][n][r];
            const float part = __shfl_xor(v, 1);
            const int nn = nn0 + r;
            const int pidx = (b*N_ + nn)*32 + (d >> 1);
            const float c = cosT[pidx], sn = sinT[pidx];
            const float rot = (d & 1) ? (v*c + part*sn) : (v*c - part*sn);
            const u16 val = f2bf(rot);
            if (s3 == 0) qo[(hb*N_ + nn)*64 + d] = val;
            else         ko[(hb*N_ + nn)*64 + d] = val;
          }
        }
      } else {
#pragma unroll
        for (int r = 0; r < 4; ++r){
          const int grow = m0 + wm*(BM/2) + m*16 + g4*4 + r;
          const int gcol = n0 + wn*64 + n*16 + r16;
          outf[(size_t)grow*Nc + gcol] = acc[m][n][r];
        }
      }
    }
  }
}

// ---------------- fused attention: QBLK=128 (8 waves), triple-tile staging ----------------
#define PST 68   // P LDS row stride: 34 dwords -> uniform bank distribution for b64 ops
__global__ __launch_bounds__(512) void k_attn(
    const u16* __restrict__ qb, const u16* __restrict__ kb, const u16* __restrict__ vt,
    const int* __restrict__ mods, u16* __restrict__ xo)
{
  __shared__ u16 lK[3][64*64];
  __shared__ u16 lV[3][64*64];
  __shared__ u16 lP[8*16*PST];
  const int tid = threadIdx.x, wid = tid >> 6, lane = tid & 63;
  const int id = blockIdx.x;          // 0..511
  const int xcd = id & 7, rank = id >> 3;   // rank 0..63 per XCD
  const int bh = xcd + 8*(rank & 3);
  const int qslot = rank >> 2;        // 0..15
  const int tp = (qslot < 8) ? (15 - qslot) : (qslot - 8);  // complementary pairs
  const int b = bh >> 4, h = bh & 15;
  const int r16 = lane & 15, g4 = lane >> 4;
  const int srow = lane >> 3, sch = lane & 7;
  int moff[4], mend[4];
#pragma unroll
  for (int m = 0; m < 4; ++m){
    moff[m] = mods[(b*4+m)*3+1];
    mend[m] = moff[m] + mods[(b*4+m)*3+2];
  }
  const u16* kbase = kb + (size_t)bh*N_*64;
  const u16* vbase = vt + (size_t)bh*64*N_;
  u16* lPw = &lP[wid*16*PST];

  const int q0 = tp*128 + wid*16;     // this wave's 16 q-rows
  const int i  = q0 + r16;            // this lane's q-row
  const int imax = tp*128 + 127;      // block max q-row (block-uniform skip)
  int jmax = 0, jmax0 = 0;
#pragma unroll
  for (int m = 0; m < 4; ++m){
    if (i  >= moff[m]) jmax  = max(jmax,  mend[m]);
    if (q0 >= moff[m]) jmax0 = max(jmax0, mend[m]);
  }
  const int thrmin = max(q0, jmax0 - 1);   // wave-uniform lower bound of thr
  const int thrg = max(i, jmax - 1);       // per-lane keep threshold (global)
  const u16* qrow = qb + ((size_t)bh*N_ + q0 + r16)*64;
  const bf16x8 aq0 = *(const bf16x8*)&qrow[g4*8];
  const bf16x8 aq1 = *(const bf16x8*)&qrow[32 + g4*8];
  f32x4 o[4] = {};
  f32x4 acc_s = {};                      // row-sum accumulator (ones-MFMA)
  bf16x8 ones;
#pragma unroll
  for (int j = 0; j < 8; ++j) ones[j] = (short)0x3F80;  // bf16 1.0

  // g2(s) = 50*tanh(s*0.125/50)*log2e as odd series in s (w = s^2), 2 terms
  const float D1 = 0.18033688011112043f;
  const float D3 = -3.7570183356483704e-07f;

  auto proc = [&](int kt)->bool{
    if (kt >= 32) return false;
    if (kt*64 <= imax) return true;
    bool p = false;
#pragma unroll
    for (int m = 0; m < 4; ++m)
      if (imax >= moff[m] && kt*64 < mend[m]) p = true;
    return p;
  };

  auto computeHalf = [&](int kt, const u16* lKc, const u16* lVc){
    // S^T = K @ Q^T : lane holds q = q0+r16, k_local = cb*16 + g4*4 + r
    f32x4 s[4] = {};
    __builtin_amdgcn_s_setprio(1);
#pragma unroll
    for (int cb = 0; cb < 4; ++cb){
#pragma unroll
      for (int t = 0; t < 2; ++t){
        int row = cb*16 + r16;
        int ch = (t*4 + g4) ^ (row & 7);
        bf16x8 bk = *(const bf16x8*)&lKc[row*64 + ch*8];
        s[cb] = __builtin_amdgcn_mfma_f32_16x16x32_bf16(bk, t ? aq1 : aq0, s[cb], 0, 0, 0);
      }
    }
    __builtin_amdgcn_s_setprio(0);
    const int thr = thrg - kt*64;                    // keep <=> k_local <= thr
    const bool nomask = (kt*64 + 63 <= thrmin);      // wave-uniform fully-kept tile
#pragma unroll
    for (int cb = 0; cb < 4; ++cb){
      float p[4];
#pragma unroll
      for (int r = 0; r < 4; ++r){
        const float sv = s[cb][r];
        const float w = sv*sv;
        p[r] = EXP2F(sv * fmaf(w, D3, D1));
      }
      if (!nomask){
#pragma unroll
        for (int r = 0; r < 4; ++r)
          p[r] = (cb*16 + g4*4 + r <= thr) ? p[r] : 0.0f;
      }
      uint32_t w01, w23;
      asm("v_cvt_pk_bf16_f32 %0, %1, %2" : "=v"(w01) : "v"(p[0]), "v"(p[1]));
      asm("v_cvt_pk_bf16_f32 %0, %1, %2" : "=v"(w23) : "v"(p[2]), "v"(p[3]));
      *reinterpret_cast<uint2*>(&lPw[r16*PST + cb*16 + g4*4]) = make_uint2(w01, w23);
    }
    asm volatile("s_waitcnt lgkmcnt(0)" ::: "memory");
    __builtin_amdgcn_sched_barrier(0);
    union { uint2 hh[2]; bf16x8 v; } u0, u1;
    u0.hh[0] = *(const uint2*)&lPw[r16*PST + g4*8];
    u0.hh[1] = *(const uint2*)&lPw[r16*PST + g4*8 + 4];
    u1.hh[0] = *(const uint2*)&lPw[r16*PST + 32 + g4*8];
    u1.hh[1] = *(const uint2*)&lPw[r16*PST + 32 + g4*8 + 4];
    __builtin_amdgcn_s_setprio(1);
    acc_s = __builtin_amdgcn_mfma_f32_16x16x32_bf16(u0.v, ones, acc_s, 0, 0, 0);
    acc_s = __builtin_amdgcn_mfma_f32_16x16x32_bf16(u1.v, ones, acc_s, 0, 0, 0);
#pragma unroll
    for (int cb = 0; cb < 4; ++cb){
#pragma unroll
      for (int t = 0; t < 2; ++t){
        int d = cb*16 + r16;
        int ch = (t*4 + g4) ^ (d & 7);
        bf16x8 bv = *(const bf16x8*)&lVc[d*64 + ch*8];
        o[cb] = __builtin_amdgcn_mfma_f32_16x16x32_bf16(t ? u1.v : u0.v, bv, o[cb], 0, 0, 0);
      }
    }
    __builtin_amdgcn_s_setprio(0);
  };

  auto stage = [&](int kt, int bi){
    const int gch = sch ^ srow;
    GLL16(kbase + (size_t)(kt*64 + wid*8 + srow)*64 + gch*8, &lK[bi][wid*512]);
    GLL16(vbase + (size_t)(wid*8 + srow)*N_ + kt*64 + gch*8, &lV[bi][wid*512]);
  };

  for (int base = 0; base < 32; base += 3){
    const bool pA = proc(base);
    const bool pB = proc(base + 1);
    const bool pC = proc(base + 2);
    if (!(pA || pB || pC)) continue;    // block-uniform skip (whole group dead)
    __syncthreads();                    // previous-group readers done
    if (pA) stage(base,     0);
    if (pB) stage(base + 1, 1);
    if (pC) stage(base + 2, 2);
    __syncthreads();                    // all staged (one vmcnt drain)
    if (pA) computeHalf(base,     lK[0], lV[0]);
    if (pB) computeHalf(base + 1, lK[1], lV[1]);
    if (pC) computeHalf(base + 2, lK[2], lV[2]);
  }
  // acc_s[r] = full row-sum for q-row g4*4+r (replicated across col lanes)
#pragma unroll
  for (int r = 0; r < 4; ++r){
    const float linv = RCPF(acc_s[r]);
    const int iq = q0 + g4*4 + r;
#pragma unroll
    for (int cb = 0; cb < 4; ++cb)
      xo[(size_t)(b*N_ + iq)*DIM_ + h*64 + cb*16 + r16] = f2bf(o[cb][r]*linv);
  }
}

extern "C" void kernel_launch(void* const* d_in, const int* in_sizes, int n_in,
                              void* d_out, int out_size, void* d_ws, size_t ws_size,
                              hipStream_t stream){
  const float* x     = (const float*)d_in[0];
  const int*   mods  = (const int*)d_in[1];
  const float* gamma = (const float*)d_in[2];
  const float* wqkv  = (const float*)d_in[3];
  const float* wout  = (const float*)d_in[4];
  float* outp = (float*)d_out;

  char* p = (char*)d_ws;
  auto alloc = [&](size_t bytes) -> char* {
    char* r = p; p += (bytes + 255) & ~(size_t)255; return r;
  };
  float* cosT  = (float*)alloc((size_t)B_*N_*32*4);
  float* sinT  = (float*)alloc((size_t)B_*N_*32*4);
  u16* wqkvT   = (u16*)alloc((size_t)NH3*DIM_*2);
  u16* woutT   = (u16*)alloc((size_t)DIM_*DIM_*2);
  u16* xn      = (u16*)alloc((size_t)ROWS*DIM_*2);
  u16* qbb     = (u16*)alloc((size_t)BHN*64*2);
  u16* kbb     = (u16*)alloc((size_t)BHN*64*2);
  u16* vtb     = (u16*)alloc((size_t)BHN*64*2);
  u16* xo      = (u16*)alloc((size_t)ROWS*DIM_*2);

  k_prep<<<8704, 256, 0, stream>>>(x, gamma, wqkv, wout, mods, xn, wqkvT, woutT, cosT, sinT);
  k_gemm<0,128,1><<<dim3(ROWS/128, NH3/128), 256, 0, stream>>>(xn, wqkvT, DIM_, NH3, nullptr, cosT, sinT, qbb, kbb, vtb);
  k_attn<<<512, 512, 0, stream>>>(qbb, kbb, vtb, mods, xo);
  k_gemm<1,64,3><<<dim3(ROWS/64, DIM_/128), 256, 0, stream>>>(xo, woutT, DIM_, DIM_, outp, nullptr, nullptr, nullptr, nullptr, nullptr);
}